// Round 7
// baseline (421.054 us; speedup 1.0000x reference)
//
#include <hip/hip_runtime.h>

typedef __attribute__((ext_vector_type(4)))  float f32x4;
typedef __attribute__((ext_vector_type(16))) float f32x16;
typedef __attribute__((ext_vector_type(8)))  short s16x8;
typedef __attribute__((ext_vector_type(4)))  short s16x4;

// B=512, T=256, E=384, H=64.  M = B*T = 131072 rows.

__device__ inline short f2bf(float f){
  unsigned u = __float_as_uint(f);
  u = u + 0x7fffu + ((u >> 16) & 1u);   // round-to-nearest-even
  return (short)(u >> 16);
}

// ---------------- Kernel 0: Wt[n][k] = W_{n/64}[k][n%64]  (bf16) ----------------
__global__ void wt_prep_kernel(const float* __restrict__ Wq, const float* __restrict__ Wk,
                               const float* __restrict__ Wv, short* __restrict__ Wt){
  int o = blockIdx.x * 256 + threadIdx.x;
  if (o >= 192*384) return;
  int n = o / 384, k = o - n*384;
  const float* W = (n < 64) ? Wq : (n < 128) ? Wk : Wv;
  Wt[o] = f2bf(W[k*64 + (n & 63)]);
}

// ---------------- Kernel 1: QKV projection v4 (coalesced x via LDS) ----------
// R6 diagnosis: per-lane row-strided x loads = 32 lines/instr -> MSHR-bound at
// 1.6 TB/s. Fix: block = 64 rows; stage x[64][384] fp32 with FLAT coalesced
// loads (1 KB contiguous per wave-instr), cvt bf16 once, padded LDS [64][392]
// (stride-392 b128 frag reads measured 0 conflicts in R6). ONE barrier, then
// barrier-free 24-step MFMA loop: B-frags from LDS, A-frags (Wt) from
// global/L2 (147 KB, reused x4/line). LDS 50 KB -> 3 blocks/CU: inter-block
// overlap of staging vs compute. Conversion VALU is out of the inner loop.
__global__ __launch_bounds__(256, 4) void proj_kernel(const float* __restrict__ x,
                            const short* __restrict__ Wt,
                            short* __restrict__ Q, short* __restrict__ K,
                            short* __restrict__ Vt){
  __shared__ __align__(16) short Xs[64*392];     // 50176 B; stride 392 = 196 dw == 4 mod 32

  const int tid  = threadIdx.x;
  const int w    = tid >> 6, lane = tid & 63;
  const int l31  = lane & 31, hh = lane >> 5;
  const int ch   = (w & 1) * 96;                 // column half (0 / 96)
  const int rh   = (w >> 1) * 32;                // row half (0 / 32)
  const long row0 = (long)blockIdx.x * 64;

  // ---- Stage x block: flat coalesced fp32 loads -> bf16 LDS ----
  const float* xb = x + row0*384;
  #pragma unroll
  for (int i = 0; i < 24; ++i){
    const int f4  = i*256 + tid;                 // 0..6143 float4s, lane-contiguous
    const int row = f4 / 96, k = (f4 % 96) * 4;
    float4 v = *(const float4*)(xb + (long)f4*4);
    s16x4 o;
    o[0]=f2bf(v.x); o[1]=f2bf(v.y); o[2]=f2bf(v.z); o[3]=f2bf(v.w);
    *(s16x4*)(Xs + row*392 + k) = o;
  }
  __syncthreads();                               // the ONLY barrier

  // ---- Barrier-free MFMA loop: wave tile 32 rows x 96 cols ----
  f32x16 acc[3];
  #pragma unroll
  for (int c = 0; c < 3; ++c)
    #pragma unroll
    for (int q = 0; q < 16; ++q) acc[c][q] = 0.0f;

  #pragma unroll
  for (int s = 0; s < 24; ++s){                  // K-step of 16 (k = s*16 + hh*8 + j)
    s16x8 bx = *(const s16x8*)(Xs + (rh + l31)*392 + s*16 + hh*8);  // B[k][row]
    #pragma unroll
    for (int c = 0; c < 3; ++c){                 // A[m=outcol][k] from global (L2-hot)
      s16x8 wa = *(const s16x8*)(Wt + (ch + c*32 + l31)*384 + s*16 + hh*8);
      acc[c] = __builtin_amdgcn_mfma_f32_32x32x16_bf16(wa, bx, acc[c], 0, 0, 0);
    }
  }

  // ---- Epilogue: C col(n)=row=l31, m=(reg&3)+8*(reg>>2)+4*hh = outcol ----
  const long trow = row0 + rh + l31;
  #pragma unroll
  for (int c = 0; c < 3; ++c){
    const int n0 = ch + c*32;
    if (n0 < 128){                               // Q (0,32) / K (64,96): [t][h]
      short* dst = (n0 < 64) ? (Q + trow*64 + n0) : (K + trow*64 + (n0 - 64));
      #pragma unroll
      for (int g = 0; g < 4; ++g){
        s16x4 v;
        #pragma unroll
        for (int i = 0; i < 4; ++i) v[i] = f2bf(acc[c][g*4 + i]);
        *(s16x4*)(dst + 8*g + 4*hh) = v;
      }
    } else {                                     // V -> Vt[b][h][t]
      short* vb = Vt + (trow >> 8)*16384 + (trow & 255);
      #pragma unroll
      for (int reg = 0; reg < 16; ++reg){
        const int h = (n0 - 128) + (reg & 3) + 8*(reg >> 2) + 4*hh;
        vb[h*256] = f2bf(acc[c][reg]);
      }
    }
  }
}

// ---------------- Kernel 2: causal attention (R2 verbatim — known good) -------
__global__ __launch_bounds__(256) void attn_kernel(const short* __restrict__ Q, const short* __restrict__ K,
                            const short* __restrict__ Vt, float* __restrict__ out){
  __shared__ __align__(16) short P[4][16*40];  // per-wave 16 x 32 chunk, stride 40
  const int tid  = threadIdx.x;
  const int w    = tid >> 6, lane = tid & 63;
  const int l15  = lane & 15, quad = lane >> 4;
  const int b    = blockIdx.x >> 2, qt = blockIdx.x & 3;
  const int qbase = qt*64 + w*16;
  const int NFw  = (qbase >> 4) + 1;           // causal key-frags needed (1..16)
  const int NSw  = (NFw + 1) >> 1;             // 32-key PV steps (1..8)

  const short* Qs = Q  + ((long)b*256 + qbase)*64;
  const short* Ks = K  + (long)b*256*64;
  const short* Vs = Vt + (long)b*64*256;

  // A frags: A[m=lane&15][k=(lane>>4)*8+j]
  s16x8 qf0 = *(const s16x8*)(Qs + l15*64 + quad*8);
  s16x8 qf1 = *(const s16x8*)(Qs + l15*64 + 32 + quad*8);

  f32x4 sc[16];
  #pragma unroll
  for (int f = 0; f < 16; ++f){
    f32x4 a;
    #pragma unroll
    for (int r = 0; r < 4; ++r) a[r] = 0.0f;
    if (f < NFw){
      const short* kp = Ks + (f*16 + l15)*64 + quad*8;   // B[k][n=key]
      s16x8 k0v = *(const s16x8*)kp;
      s16x8 k1v = *(const s16x8*)(kp + 32);
      a = __builtin_amdgcn_mfma_f32_16x16x32_bf16(qf0, k0v, a, 0, 0, 0);
      a = __builtin_amdgcn_mfma_f32_16x16x32_bf16(qf1, k1v, a, 0, 0, 0);
    }
    sc[f] = a;
  }

  // softmax: C col=key=f*16+(lane&15), row=query=quad*4+reg
  float mx[4], sm[4];
  #pragma unroll
  for (int r = 0; r < 4; ++r) mx[r] = -3.0e38f;
  #pragma unroll
  for (int f = 0; f < 16; ++f){
    if (f < NFw){
      const int key = f*16 + l15;
      #pragma unroll
      for (int r = 0; r < 4; ++r){
        const int qg = qbase + quad*4 + r;
        float s = sc[f][r] * 0.125f;               // d^-0.5, H=64
        s = (key <= qg) ? s : -1.0e30f;
        sc[f][r] = s;
        mx[r] = fmaxf(mx[r], s);
      }
    }
  }
  #pragma unroll
  for (int r = 0; r < 4; ++r){
    #pragma unroll
    for (int off = 1; off < 16; off <<= 1) mx[r] = fmaxf(mx[r], __shfl_xor(mx[r], off, 16));
  }
  #pragma unroll
  for (int r = 0; r < 4; ++r) sm[r] = 0.0f;
  #pragma unroll
  for (int f = 0; f < 16; ++f){
    if (f < NFw){
      #pragma unroll
      for (int r = 0; r < 4; ++r){
        float p = exp2f((sc[f][r] - mx[r]) * 1.44269504f);
        sc[f][r] = p;
        sm[r] += p;
      }
    }
  }
  #pragma unroll
  for (int r = 0; r < 4; ++r){
    #pragma unroll
    for (int off = 1; off < 16; off <<= 1) sm[r] += __shfl_xor(sm[r], off, 16);
  }

  // PV: out[16q x 64h], A = P via LDS round-trip, B = Vt rows
  f32x4 o[4];
  #pragma unroll
  for (int h = 0; h < 4; ++h)
    #pragma unroll
    for (int r = 0; r < 4; ++r) o[h][r] = 0.0f;

  short* Pw = P[w];
  #pragma unroll
  for (int ks = 0; ks < 8; ++ks){
    if (ks < NSw){
      #pragma unroll
      for (int fi = 0; fi < 2; ++fi){
        const int f = 2*ks + fi;
        #pragma unroll
        for (int r = 0; r < 4; ++r){
          short v = 0;
          if (f < NFw) v = f2bf(sc[f][r]);
          Pw[(quad*4 + r)*40 + fi*16 + l15] = v;
        }
      }
      s16x8 pf = *(const s16x8*)(Pw + l15*40 + quad*8);  // A[m=l15][k=quad*8+j]
      #pragma unroll
      for (int h = 0; h < 4; ++h){
        s16x8 vf = *(const s16x8*)(Vs + (h*16 + l15)*256 + ks*32 + quad*8);
        o[h] = __builtin_amdgcn_mfma_f32_16x16x32_bf16(pf, vf, o[h], 0, 0, 0);
      }
    }
  }

  float* op = out + ((long)b*256 + qbase)*64;
  #pragma unroll
  for (int r = 0; r < 4; ++r){
    const float inv = 1.0f / sm[r];
    #pragma unroll
    for (int h = 0; h < 4; ++h)
      op[(quad*4 + r)*64 + h*16 + l15] = o[h][r] * inv;
  }
}

extern "C" void kernel_launch(void* const* d_in, const int* in_sizes, int n_in,
                              void* d_out, int out_size, void* d_ws, size_t ws_size,
                              hipStream_t stream){
  const float* x  = (const float*)d_in[0];
  const float* Wq = (const float*)d_in[1];
  const float* Wk = (const float*)d_in[2];
  const float* Wv = (const float*)d_in[3];
  float* out = (float*)d_out;

  char* ws = (char*)d_ws;
  short* Wt = (short*)ws;                                  // 147456 B
  short* Q  = (short*)(ws + 147456);                       // 16.78 MB
  short* K  = (short*)(ws + 147456 + 16777216);
  short* Vt = (short*)(ws + 147456 + 2*16777216);          // [b][h][t]

  hipLaunchKernelGGL(wt_prep_kernel, dim3(288),  dim3(256), 0, stream, Wq, Wk, Wv, Wt);
  hipLaunchKernelGGL(proj_kernel,    dim3(2048), dim3(256), 0, stream, x, Wt, Q, K, Vt);
  hipLaunchKernelGGL(attn_kernel,    dim3(2048), dim3(256), 0, stream, Q, K, Vt, out);
}